// Round 7
// baseline (158.875 us; speedup 1.0000x reference)
//
#include <hip/hip_runtime.h>
#include <float.h>

// Quantize: z [8,4096,512] f32, embed_w [512,128] f32, GROUPS=4
// flat = z.reshape(131072,128); dist to 512 codes; argmin; gather; MSE scalar.
// d_out (f32): z_q_st [16777216], diff [1], ind [131072] (as float).
//
// Single-kernel design: fp16-hi codebook (128 KB) converted inline and
// resident in LDS, ONE barrier total; afterwards every wave runs fully
// independently (scan, reduce, flag, exact-fp64 refine, gather, store).
// Scores a = x16.w16 - 0.5*||w||^2 via MFMA; rows with top-2 margin < TAU_A
// are re-solved exactly in fp64 against fp32 W => exact argmin indices.

typedef _Float16 half8 __attribute__((ext_vector_type(8)));
typedef __attribute__((ext_vector_type(4))) float f32x4;

constexpr int Dn = 128;
constexpr int K  = 512;
constexpr long long Mrows = 131072;
constexpr int RPW   = 32;                    // rows per wave
constexpr int WAVES = 16;                    // waves per block (1024 threads)
constexpr int RPB   = RPW * WAVES;           // 512 rows per block
constexpr int NBLK  = (int)(Mrows / RPB);    // 256
constexpr float TAU_A = 0.05f;               // score-margin for fp64 re-solve

constexpr size_t ZQ_SIZE  = (size_t)Mrows * Dn;
constexpr size_t DIFF_OFF = ZQ_SIZE;
constexpr size_t IND_OFF  = ZQ_SIZE + 1;

__global__ __launch_bounds__(1024, 4) void vq_main(
        const float* __restrict__ Z, const float* __restrict__ W,
        float* __restrict__ out, double* __restrict__ diffsum) {
    __shared__ __align__(16) char Wlds[131072];   // full codebook, fp16 hi, swizzled
    __shared__ float wn2_s[K];                    // -0.5*||w||^2
    __shared__ float xn_s[RPB];
    __shared__ int   sIdx[RPB];
    __shared__ int   sFlag[RPB];

    const int tid  = threadIdx.x;
    const int w    = tid >> 6;
    const int lane = tid & 63;
    const int lm   = lane & 15;        // A row / B col within 16-tile
    const int lg   = lane >> 4;        // k-block (0..3)
    const size_t row0 = (size_t)blockIdx.x * RPB;

    // ---- A) inline codebook stage: fp32 W -> fp16 hi, XOR-swizzled LDS ----
    // thread owns code = tid>>1, dims [h*64, h*64+64) (granules h*8..h*8+7)
    {
        const int code = tid >> 1, h = tid & 1;
        const float4* ws4 = (const float4*)(W + (size_t)code * Dn + h * 64);
        float s2 = 0.f;
        #pragma unroll
        for (int g8 = 0; g8 < 8; ++g8) {
            float4 a = ws4[g8 * 2];
            float4 b = ws4[g8 * 2 + 1];
            float vv[8] = {a.x, a.y, a.z, a.w, b.x, b.y, b.z, b.w};
            half8 hv;
            #pragma unroll
            for (int j = 0; j < 8; ++j) {
                hv[j] = (_Float16)vv[j];
                s2 += vv[j] * vv[j];
            }
            const int g = h * 8 + g8;
            *(half8*)(Wlds + code * 256 + ((g ^ (code & 7)) << 4)) = hv;
        }
        s2 += __shfl_xor(s2, 1);
        if (!h) wn2_s[code] = -0.5f * s2;
    }

    // ---- B) X fragments (fp16) + row norms (overlaps A's loads) ----
    half8 ah[2][4];                     // [16-row tile][ks]
    #pragma unroll
    for (int r = 0; r < 2; ++r) {
        const size_t grow = row0 + (size_t)w * RPW + r * 16 + lm;
        float s2 = 0.f;
        #pragma unroll
        for (int ks = 0; ks < 4; ++ks) {
            const float* xp = Z + grow * Dn + ks * 32 + lg * 8;
            float4 x0 = *(const float4*)xp;
            float4 x1 = *(const float4*)(xp + 4);
            float xv[8] = {x0.x, x0.y, x0.z, x0.w, x1.x, x1.y, x1.z, x1.w};
            #pragma unroll
            for (int j = 0; j < 8; ++j) {
                ah[r][ks][j] = (_Float16)xv[j];
                s2 += xv[j] * xv[j];
            }
        }
        s2 += __shfl_xor(s2, 16);
        s2 += __shfl_xor(s2, 32);      // full ||x||^2 for row grow
        if (lg == 0) xn_s[w * RPW + r * 16 + lm] = s2;
    }

    float m1[2][4], m2[2][4];
    int   i1[2][4];
    #pragma unroll
    for (int r = 0; r < 2; ++r)
        #pragma unroll
        for (int j = 0; j < 4; ++j) { m1[r][j] = -FLT_MAX; m2[r][j] = -FLT_MAX; i1[r][j] = 0; }

    __syncthreads();                   // codebook + wn2 resident: the ONLY barrier

    // ---- C) main scan: 32 B-tiles, per-wave staggered start, no syncs ----
    const int t0 = (w * 2) & 31;
    #pragma unroll 2
    for (int ti = 0; ti < 32; ++ti) {
        const int t = (ti + t0) & 31;
        const int code = t * 16 + lm;
        const float cinit = wn2_s[code];
        half8 bh[4];
        #pragma unroll
        for (int ks = 0; ks < 4; ++ks) {
            const int off = code * 256 + ((((ks << 2) + lg) ^ (code & 7)) << 4);
            bh[ks] = *(const half8*)(Wlds + off);
        }
        f32x4 acc[2];
        #pragma unroll
        for (int r = 0; r < 2; ++r) acc[r] = (f32x4){cinit, cinit, cinit, cinit};
        #pragma unroll
        for (int ks = 0; ks < 4; ++ks) {
            #pragma unroll
            for (int r = 0; r < 2; ++r)
                acc[r] = __builtin_amdgcn_mfma_f32_16x16x32_f16(ah[r][ks], bh[ks], acc[r], 0, 0, 0);
        }
        #pragma unroll
        for (int r = 0; r < 2; ++r) {
            #pragma unroll
            for (int j = 0; j < 4; ++j) {
                const float a = acc[r][j];
                m2[r][j] = __builtin_amdgcn_fmed3f(a, m1[r][j], m2[r][j]);
                const bool gt = a > m1[r][j];
                m1[r][j] = fmaxf(m1[r][j], a);
                i1[r][j] = gt ? code : i1[r][j];
            }
        }
    }

    // ---- D) reduce (m1, idx, m2) across the 16 col-lanes (wave-local) ----
    #pragma unroll
    for (int sft = 1; sft < 16; sft <<= 1) {
        #pragma unroll
        for (int r = 0; r < 2; ++r) {
            #pragma unroll
            for (int j = 0; j < 4; ++j) {
                float o1 = __shfl_xor(m1[r][j], sft);
                float o2 = __shfl_xor(m2[r][j], sft);
                int   oi = __shfl_xor(i1[r][j], sft);
                if (o1 > m1[r][j] || (o1 == m1[r][j] && oi < i1[r][j])) {
                    m2[r][j] = fmaxf(m1[r][j], o2);
                    m1[r][j] = o1;
                    i1[r][j] = oi;
                } else {
                    m2[r][j] = fmaxf(m2[r][j], o1);
                }
            }
        }
    }

    float psum = 0.f;
    if (lm == 0) {
        #pragma unroll
        for (int r = 0; r < 2; ++r) {
            #pragma unroll
            for (int j = 0; j < 4; ++j) {
                const int row = w * RPW + r * 16 + lg * 4 + j;   // C row = lg*4 + reg
                sIdx[row]  = i1[r][j];
                sFlag[row] = (m1[r][j] - m2[r][j] < TAU_A) ? 1 : 0;
                psum += xn_s[row] - 2.f * m1[r][j];              // dist^2 = ||x||^2 - 2a
            }
        }
    }
    // (wave-local LDS: ds-op ordering within the wave, no barrier needed)

    // ---- E) fp64 exact refinement of this wave's near-tie rows (rare) ----
    {
        const int cg    = lane >> 3;           // code subgroup 0..7
        const int dbase = (lane & 7) * 16;     // 16-dim slice per lane
        unsigned long long fl = __ballot(lane < 32 && sFlag[w * RPW + (lane & 31)] != 0);
        while (fl) {
            const int rr = __ffsll(fl) - 1;    // wave-local row 0..31
            fl &= fl - 1;
            const float* xp = Z + (row0 + w * RPW + rr) * Dn + dbase;
            double xd[16];
            #pragma unroll
            for (int q = 0; q < 16; q += 4) {
                float4 v = *(const float4*)(xp + q);
                xd[q] = v.x; xd[q+1] = v.y; xd[q+2] = v.z; xd[q+3] = v.w;
            }
            double best = 1e300; int bi = 0;
            for (int cb = 0; cb < 64; ++cb) {
                const int c = cb * 8 + cg;
                const float* wp = W + (size_t)c * Dn + dbase;
                double s = 0.0;
                #pragma unroll
                for (int q = 0; q < 16; q += 4) {
                    float4 wv = *(const float4*)(wp + q);
                    double d0 = xd[q]   - (double)wv.x;
                    double d1 = xd[q+1] - (double)wv.y;
                    double d2 = xd[q+2] - (double)wv.z;
                    double d3 = xd[q+3] - (double)wv.w;
                    s += d0 * d0 + d1 * d1 + d2 * d2 + d3 * d3;
                }
                s += __shfl_xor(s, 1);
                s += __shfl_xor(s, 2);
                s += __shfl_xor(s, 4);         // all 8 lanes of group hold s(c)
                if (s < best) { best = s; bi = c; }   // ascending c => min-idx tiebreak
            }
            #pragma unroll
            for (int sft = 8; sft < 64; sft <<= 1) {
                double ob = __shfl_xor(best, sft);
                int    ok = __shfl_xor(bi, sft);
                if (ob < best || (ob == best && ok < bi)) { best = ob; bi = ok; }
            }
            if (lane == 0) sIdx[w * RPW + rr] = bi;
        }
    }

    // ---- F) per-wave epilogue: gather W[ind], store z_q_st, ind, diff ----
    #pragma unroll
    for (int it = 0; it < 16; ++it) {
        int f4i = lane + it * 64;              // 0..1023
        int rl  = f4i >> 5, cq = f4i & 31;     // 32 rows x 32 float4
        int ind = sIdx[w * RPW + rl];
        float4 wv = ((const float4*)(W + (size_t)ind * Dn))[cq];
        ((float4*)(out + (row0 + w * RPW + rl) * Dn))[cq] = wv;
    }
    if (lane < RPW)
        out[IND_OFF + row0 + w * RPW + lane] = (float)sIdx[w * RPW + lane];

    #pragma unroll
    for (int sft = 1; sft < 64; sft <<= 1) psum += __shfl_xor(psum, sft);
    if (lane == 0) atomicAdd(diffsum, (double)psum);
}

__global__ void diff_kernel(const double* __restrict__ diffsum, float* __restrict__ out) {
    if (threadIdx.x == 0 && blockIdx.x == 0) {
        // KLD_SCALE * (COMMITMENT_COST + 1) * mean = 12.5 * mean
        out[DIFF_OFF] = (float)(12.5 * diffsum[0] / (double)ZQ_SIZE);
    }
}

extern "C" void kernel_launch(void* const* d_in, const int* in_sizes, int n_in,
                              void* d_out, int out_size, void* d_ws, size_t ws_size,
                              hipStream_t stream) {
    (void)in_sizes; (void)n_in; (void)out_size; (void)ws_size;
    const float* Z = (const float*)d_in[0];
    const float* W = (const float*)d_in[1];
    float* out = (float*)d_out;
    double* diffsum = (double*)d_ws;

    hipMemsetAsync(d_ws, 0, 16, stream);
    vq_main<<<NBLK, 1024, 0, stream>>>(Z, W, out, diffsum);
    diff_kernel<<<1, 64, 0, stream>>>(diffsum, out);
}